// Round 19
// baseline (248.469 us; speedup 1.0000x reference)
//
#include <hip/hip_runtime.h>
#include <hip/hip_bf16.h>

#define NN   10000
#define NP   10048          // 157*64 padded rows
#define HID  256
#define BN_EPS 1e-5f
#define NPH  ((size_t)NP * 256)

typedef _Float16 f16x4 __attribute__((ext_vector_type(4)));
typedef _Float16 f16x8 __attribute__((ext_vector_type(8)));
typedef float    f32x4 __attribute__((ext_vector_type(4)));

__device__ __forceinline__ void gl_lds16(const void* gptr, void* lptr) {
    __builtin_amdgcn_global_load_lds(
        (const __attribute__((address_space(1))) void*)gptr,
        (__attribute__((address_space(3))) void*)lptr,
        16, 0, 0);
}

__device__ __forceinline__ f32x4 cvt4(const _Float16* p) {
    f16x4 t = *(const f16x4*)p;
    f32x4 r; r[0] = t[0]; r[1] = t[1]; r[2] = t[2]; r[3] = t[3];
    return r;
}

// 8-wide fp16 load -> two f32x4
__device__ __forceinline__ void cvt8(const _Float16* p, f32x4& lo, f32x4& hi) {
    f16x8 t = *(const f16x8*)p;
    lo[0] = t[0]; lo[1] = t[1]; lo[2] = t[2]; lo[3] = t[3];
    hi[0] = t[4]; hi[1] = t[5]; hi[2] = t[6]; hi[3] = t[7];
}

// ------------------------------------------------------------------
// Merged: cnt-zero + i64-layout detect (blocks 0..39), weight fp16
// conversion (blocks 40..3019), BN-fold precompute (block 3020).
__global__ void prep_split(const int* __restrict__ e, unsigned* __restrict__ cnt,
                           unsigned* __restrict__ flag,
                           const float* __restrict__ in_W, const float* __restrict__ gcn_W,
                           const float* __restrict__ c1_W, const float* __restrict__ c2_W,
                           const float* __restrict__ c3_W,
                           const float* __restrict__ gcn_b, const float* __restrict__ bn_g,
                           const float* __restrict__ bn_be, const float* __restrict__ bn_m,
                           const float* __restrict__ bn_v,
                           _Float16* __restrict__ wi, _Float16* __restrict__ gw,
                           _Float16* __restrict__ c1, _Float16* __restrict__ c2,
                           _Float16* __restrict__ c3,
                           float* __restrict__ bnA, float* __restrict__ bnP2) {
    if (blockIdx.x < 40) {
        int i = blockIdx.x * 256 + threadIdx.x;
        if (i < NN) cnt[i] = 0u;
        if (blockIdx.x == 0) {
            __shared__ int nz;
            if (threadIdx.x == 0) nz = 0;
            __syncthreads();
            if (e[2 * threadIdx.x + 1] != 0) nz = 1;
            __syncthreads();
            if (threadIdx.x == 0) *flag = (nz == 0) ? 1u : 0u;  // 1 => int64 layout
        }
        return;
    }
    if (blockIdx.x == 3020) {
#pragma unroll
        for (int it = 0; it < 3; ++it) {
            int idx = it * 256 + threadIdx.x;
            if (idx < 768) {
                float a = bn_g[idx] * rsqrtf(bn_v[idx] + BN_EPS);
                bnA[idx]  = a;
                bnP2[idx] = a * (gcn_b[idx] - bn_m[idx]) + bn_be[idx];
            }
        }
        return;
    }
    int idx = (blockIdx.x - 40) * 256 + threadIdx.x;
    float v; _Float16* d; int o;
    if (idx < 524288)      { v = in_W[idx];          d = wi; o = idx; }
    else if (idx < 720896) { o = idx - 524288; v = gcn_W[o]; d = gw; }
    else if (idx < 753664) { o = idx - 720896; v = c1_W[o];  d = c1; }
    else if (idx < 761856) { o = idx - 753664; v = c2_W[o];  d = c2; }
    else                   { o = idx - 761856; int r = o >> 6, c = o & 63;
                             v = (r < 10) ? c3_W[r * 64 + c] : 0.0f; d = c3; }
    d[o] = (_Float16)v;
}

__device__ __forceinline__ int edge_val(const int* e, unsigned f, long idx) {
    return f ? e[2 * idx] : e[idx];
}

__global__ void count_edges(const int* __restrict__ e, const unsigned* __restrict__ flag,
                            unsigned* __restrict__ cnt, int E) {
    int i = blockIdx.x * blockDim.x + threadIdx.x;
    if (i >= E) return;
    unsigned f = *flag;
    atomicAdd(&cnt[edge_val(e, f, (long)E + i)], 1u);
}

// single block, 1024 threads
__global__ void scan_dinv(const unsigned* __restrict__ cnt, unsigned* __restrict__ off,
                          unsigned* __restrict__ cur, float* __restrict__ dinv, int n) {
    __shared__ unsigned partial[1024];
    int t = threadIdx.x;
    int chunk = (n + 1023) / 1024;
    int lo = t * chunk;
    int hi = lo + chunk; if (hi > n) hi = n; if (lo > n) lo = n;
    unsigned s = 0;
    for (int i = lo; i < hi; ++i) s += cnt[i];
    partial[t] = s;
    __syncthreads();
    for (int d = 1; d < 1024; d <<= 1) {
        unsigned v = (t >= d) ? partial[t - d] : 0u;
        __syncthreads();
        partial[t] += v;
        __syncthreads();
    }
    unsigned base = (t == 0) ? 0u : partial[t - 1];
    for (int i = lo; i < hi; ++i) {
        off[i] = base; cur[i] = base;
        dinv[i] = rsqrtf((float)cnt[i] + 1.0f);
        base += cnt[i];
    }
    if (t == 1023) off[n] = base;
}

__global__ void fill_csr(const int* __restrict__ e, const unsigned* __restrict__ flag,
                         unsigned* __restrict__ cur, int* __restrict__ csr_src, int E) {
    int i = blockIdx.x * blockDim.x + threadIdx.x;
    if (i >= E) return;
    unsigned f = *flag;
    int src = edge_val(e, f, (long)i);
    int dst = edge_val(e, f, (long)E + i);
    unsigned pos = atomicAdd(&cur[dst], 1u);
    csr_src[pos] = src;
}

// ------------------------------------------------------------------
// Input projection v3: BM=64 x BN=256, split-K=8. A loaded DIRECTLY per-lane
// from global fp32 (fragment rows; coalesced, read-once) + in-register cvt —
// no A LDS, so the barrier chain guards only B (gl_lds, double-buffered).
// LDS 32 KB -> 5 blk/CU. Partials FP16.
#define IPZ 8
#define IPKC 256
__global__ __launch_bounds__(256) void inproj_gemm(
    const float* __restrict__ A,
    const _Float16* __restrict__ B,
    _Float16* __restrict__ P)
{
    __shared__ __align__(16) _Float16 sB[2][8192];

    const int tid = threadIdx.x, wid = tid >> 6, lane = tid & 63;
    const int fr = lane & 15, fq = lane >> 4;
    const int bm = blockIdx.x * 64;
    const int kbase = blockIdx.z * IPKC;
    const int wn = wid * 64;

    f32x4 acc[4][4] = {};

    // per-lane direct A fragment pointers (row = bm + mi*16 + fr)
    const float* ap[4];
#pragma unroll
    for (int mi = 0; mi < 4; ++mi)
        ap[mi] = A + (size_t)min(bm + mi * 16 + fr, NN - 1) * 2048 + kbase + fq * 8;

    const int brow_l = lane >> 2, bch = lane & 3;
    int cur = 0;

    {   // prologue: stage B tile 0
#pragma unroll
        for (int j = 0; j < 4; ++j) {
            int slice = wid * 4 + j;
            int row = slice * 16 + brow_l;
            int lc = bch ^ ((row >> 1) & 3);
            gl_lds16(B + (size_t)row * 2048 + kbase + lc * 8, &sB[0][slice * 512]);
        }
    }
    __syncthreads();

    for (int kt = 0; kt < IPKC / 32; ++kt) {
        const bool more = (kt + 1) < IPKC / 32;
        if (more) {
            const int nk = kbase + (kt + 1) * 32;
#pragma unroll
            for (int j = 0; j < 4; ++j) {
                int slice = wid * 4 + j;
                int row = slice * 16 + brow_l;
                int lc = bch ^ ((row >> 1) & 3);
                gl_lds16(B + (size_t)row * 2048 + nk + lc * 8, &sB[cur ^ 1][slice * 512]);
            }
        }
        // direct per-lane A fragments (fp32 -> fp16 in reg)
        f16x8 a[4];
#pragma unroll
        for (int mi = 0; mi < 4; ++mi) {
            float4 u0 = *(const float4*)(ap[mi] + kt * 32);
            float4 u1 = *(const float4*)(ap[mi] + kt * 32 + 4);
            a[mi][0] = (_Float16)u0.x; a[mi][1] = (_Float16)u0.y;
            a[mi][2] = (_Float16)u0.z; a[mi][3] = (_Float16)u0.w;
            a[mi][4] = (_Float16)u1.x; a[mi][5] = (_Float16)u1.y;
            a[mi][6] = (_Float16)u1.z; a[mi][7] = (_Float16)u1.w;
        }
        f16x8 b[4];
#pragma unroll
        for (int ni = 0; ni < 4; ++ni) {
            int r = wn + ni * 16 + fr;
            b[ni] = *(const f16x8*)&sB[cur][r * 32 + ((fq ^ ((r >> 1) & 3)) << 3)];
        }
#pragma unroll
        for (int mi = 0; mi < 4; ++mi)
#pragma unroll
            for (int ni = 0; ni < 4; ++ni)
                acc[mi][ni] = __builtin_amdgcn_mfma_f32_16x16x32_f16(a[mi], b[ni], acc[mi][ni], 0, 0, 0);
        __syncthreads();
        cur ^= 1;
    }

    _Float16* Pz = P + (size_t)blockIdx.z * NPH;
#pragma unroll
    for (int mi = 0; mi < 4; ++mi) {
        int row0 = bm + mi * 16 + fq * 4;
#pragma unroll
        for (int ni = 0; ni < 4; ++ni) {
            int col = wn + ni * 16 + fr;
#pragma unroll
            for (int r = 0; r < 4; ++r)
                Pz[(size_t)(row0 + r) * 256 + col] = (_Float16)acc[mi][ni][r];
        }
    }
}

// reduce 8 fp16 partials + bias + relu -> single fp16 plane (zero pad rows)
__global__ void inproj_epi(const _Float16* __restrict__ P, const float* __restrict__ b,
                           _Float16* __restrict__ hh) {
    int t = blockIdx.x * 256 + threadIdx.x;
    size_t idx = (size_t)t * 4;
    int row = (int)(idx >> 8), col = (int)(idx & 255);
    float v[4] = {0, 0, 0, 0};
    if (row < NN) {
        f32x4 a0 = cvt4(P + idx)           + cvt4(P + idx + NPH);
        f32x4 a1 = cvt4(P + idx + 2 * NPH) + cvt4(P + idx + 3 * NPH);
        f32x4 a2 = cvt4(P + idx + 4 * NPH) + cvt4(P + idx + 5 * NPH);
        f32x4 a3 = cvt4(P + idx + 6 * NPH) + cvt4(P + idx + 7 * NPH);
        f32x4 bb = *(const f32x4*)(b + col);
#pragma unroll
        for (int j = 0; j < 4; ++j)
            v[j] = fmaxf((a0[j] + a1[j]) + (a2[j] + a3[j]) + bb[j], 0.0f);
    }
    f16x4 hv;
#pragma unroll
    for (int j = 0; j < 4; ++j) hv[j] = (_Float16)v[j];
    *(f16x4*)&hh[idx] = hv;
}

// ------------------------------------------------------------------
// Layer GEMM (K=256): no LDS, per-lane direct fragment loads.
// A = h single fp16, B = single fp16 weight plane; 1 pass.
// Epilogue pre-scales by dinv[row] and emits hws as FP16.
__global__ __launch_bounds__(256) void gemm_layer(
    const _Float16* __restrict__ Ah,
    const _Float16* __restrict__ Bw,
    const float* __restrict__ dinv, _Float16* __restrict__ Cw)
{
    const int tid = threadIdx.x, wid = tid >> 6, lane = tid & 63;
    const int fr = lane & 15, fq = lane >> 4;
    const int wr = wid >> 1, wc = wid & 1;
    const int bm = blockIdx.x * 64, bn = blockIdx.y * 64;

    f32x4 acc[2][2] = {};
    size_t ra[2], rb[2];
#pragma unroll
    for (int mi = 0; mi < 2; ++mi) ra[mi] = (size_t)(bm + wr * 32 + mi * 16 + fr) * 256 + fq * 8;
#pragma unroll
    for (int ni = 0; ni < 2; ++ni) rb[ni] = (size_t)(bn + wc * 32 + ni * 16 + fr) * 256 + fq * 8;

#pragma unroll
    for (int kt = 0; kt < 8; ++kt) {
        f16x8 ah[2], bw[2];
#pragma unroll
        for (int mi = 0; mi < 2; ++mi)
            ah[mi] = *(const f16x8*)(Ah + ra[mi] + kt * 32);
#pragma unroll
        for (int ni = 0; ni < 2; ++ni)
            bw[ni] = *(const f16x8*)(Bw + rb[ni] + kt * 32);
#pragma unroll
        for (int mi = 0; mi < 2; ++mi)
#pragma unroll
            for (int ni = 0; ni < 2; ++ni)
                acc[mi][ni] = __builtin_amdgcn_mfma_f32_16x16x32_f16(ah[mi], bw[ni], acc[mi][ni], 0, 0, 0);
    }

    float dv[2][4];
#pragma unroll
    for (int mi = 0; mi < 2; ++mi)
#pragma unroll
        for (int r = 0; r < 4; ++r) {
            int row = bm + wr * 32 + mi * 16 + fq * 4 + r;
            dv[mi][r] = (row < NN) ? dinv[row] : 0.0f;
        }

#pragma unroll
    for (int mi = 0; mi < 2; ++mi)
#pragma unroll
        for (int ni = 0; ni < 2; ++ni) {
            int col = bn + wc * 32 + ni * 16 + fr;
#pragma unroll
            for (int r = 0; r < 4; ++r) {
                int row = bm + wr * 32 + mi * 16 + fq * 4 + r;
                if (row < NN)
                    Cw[(size_t)row * 256 + col] = (_Float16)(acc[mi][ni][r] * dv[mi][r]);
            }
        }
}

// ------------------------------------------------------------------
// GCN aggregate v7: wave-per-node, TWO edges in flight per iteration.
//   out = relu(bnA*(dn*acc) + bnP2) (+ res); emits single fp16 plane.
__global__ __launch_bounds__(256) void gcn_aggregate(
    const _Float16* __restrict__ hws, const float* __restrict__ res,
    const float* __restrict__ dinv, const unsigned* __restrict__ off,
    const int* __restrict__ csr,
    const float* __restrict__ bnA, const float* __restrict__ bnP2,
    float* __restrict__ hf, _Float16* __restrict__ hh)
{
    const int wid = threadIdx.x >> 6, l = threadIdx.x & 63;
    const int node = blockIdx.x * 4 + wid;            // grid = 2500 blocks
    const int half = l >> 5;                          // 0 or 1
    const int q = l & 31;                             // lane-in-half
    const int f = q << 3;                             // feature base 0..248 (8 feats)
    const size_t rowf = (size_t)node * HID + f;

    const float dn = dinv[node];
    const unsigned j0 = off[node], j1 = off[node + 1];
    const unsigned deg = j1 - j0;

    f32x4 a0l = {0,0,0,0}, a0h = {0,0,0,0}, a1l = {0,0,0,0}, a1h = {0,0,0,0};
    f32x4 a2l = {0,0,0,0}, a2h = {0,0,0,0}, a3l = {0,0,0,0}, a3h = {0,0,0,0};

    if (half == 0) {   // self term in half 0
        f32x4 lo, hi; cvt8(hws + rowf, lo, hi);
        a0l += lo; a0h += hi;
    }

    unsigned i = (unsigned)half;
    for (; i + 8 <= deg; i += 8) {     // 4 edges per half per iter (stride 2)
        int s0 = csr[j0 + i];
        int s1 = csr[j0 + i + 2];
        int s2 = csr[j0 + i + 4];
        int s3 = csr[j0 + i + 6];
        f32x4 lo, hi;
        cvt8(hws + (size_t)s0 * HID + f, lo, hi); a0l += lo; a0h += hi;
        cvt8(hws + (size_t)s1 * HID + f, lo, hi); a1l += lo; a1h += hi;
        cvt8(hws + (size_t)s2 * HID + f, lo, hi); a2l += lo; a2h += hi;
        cvt8(hws + (size_t)s3 * HID + f, lo, hi); a3l += lo; a3h += hi;
    }
    for (; i < deg; i += 2) {
        int s = csr[j0 + i];
        f32x4 lo, hi;
        cvt8(hws + (size_t)s * HID + f, lo, hi); a1l += lo; a1h += hi;
    }

    f32x4 accl = (a0l + a1l) + (a2l + a3l);
    f32x4 acch = (a0h + a1h) + (a2h + a3h);

#pragma unroll
    for (int j = 0; j < 4; ++j) {
        accl[j] += __shfl_xor((float)accl[j], 32);
        acch[j] += __shfl_xor((float)acch[j], 32);
    }
    if (half) return;

    f32x4 alL = *(const f32x4*)(bnA + f);
    f32x4 alH = *(const f32x4*)(bnA + f + 4);
    f32x4 p4L = *(const f32x4*)(bnP2 + f);
    f32x4 p4H = *(const f32x4*)(bnP2 + f + 4);
    f32x4 rL = {0,0,0,0}, rH = {0,0,0,0};
    if (res) {
        rL = *(const f32x4*)(res + rowf);
        rH = *(const f32x4*)(res + rowf + 4);
    }

    f32x4 oL, oH;
    f16x8 hv;
#pragma unroll
    for (int j = 0; j < 4; ++j) {
        float t = alL[j] * (dn * accl[j]) + p4L[j];
        t = fmaxf(t, 0.0f) + rL[j];
        oL[j] = t; hv[j] = (_Float16)t;
        float u = alH[j] * (dn * acch[j]) + p4H[j];
        u = fmaxf(u, 0.0f) + rH[j];
        oH[j] = u; hv[j + 4] = (_Float16)u;
    }
    if (hf) {
        *(f32x4*)(hf + rowf)     = oL;
        *(f32x4*)(hf + rowf + 4) = oH;
    }
    *(f16x8*)&hh[rowf] = hv;
}

// ------------------------------------------------------------------
// Fused classifier: 32-row tile, h -> O1(LDS) -> O2(LDS) -> logits.
__global__ __launch_bounds__(256) void classifier(
    const _Float16* __restrict__ Ah,
    const _Float16* __restrict__ c1w, const float* __restrict__ b1,
    const _Float16* __restrict__ c2w, const float* __restrict__ b2,
    const _Float16* __restrict__ c3w, const float* __restrict__ b3,
    float* __restrict__ out)
{
    __shared__ __align__(16) float sO1[32][132];
    __shared__ __align__(16) float sO2[32][68];

    const int tid = threadIdx.x, wid = tid >> 6, lane = tid & 63;
    const int fr = lane & 15, fq = lane >> 4;
    const int bm = blockIdx.x * 32;

    // ---- stage 1: O1 = relu(h @ c1^T + b1)   M=32 N=128 K=256
    {
        f32x4 acc[2][2] = {};
        size_t ra[2], rb[2];
#pragma unroll
        for (int mi = 0; mi < 2; ++mi) ra[mi] = (size_t)(bm + mi * 16 + fr) * 256 + fq * 8;
#pragma unroll
        for (int ni = 0; ni < 2; ++ni) rb[ni] = (size_t)(wid * 32 + ni * 16 + fr) * 256 + fq * 8;
#pragma unroll
        for (int kt = 0; kt < 8; ++kt) {
            f16x8 ah[2], bw[2];
#pragma unroll
            for (int mi = 0; mi < 2; ++mi)
                ah[mi] = *(const f16x8*)(Ah + ra[mi] + kt * 32);
#pragma unroll
            for (int ni = 0; ni < 2; ++ni)
                bw[ni] = *(const f16x8*)(c1w + rb[ni] + kt * 32);
#pragma unroll
            for (int mi = 0; mi < 2; ++mi)
#pragma unroll
                for (int ni = 0; ni < 2; ++ni)
                    acc[mi][ni] = __builtin_amdgcn_mfma_f32_16x16x32_f16(ah[mi], bw[ni], acc[mi][ni], 0, 0, 0);
        }
#pragma unroll
        for (int mi = 0; mi < 2; ++mi)
#pragma unroll
            for (int ni = 0; ni < 2; ++ni) {
                int col = wid * 32 + ni * 16 + fr;
                float bb = b1[col];
#pragma unroll
                for (int r = 0; r < 4; ++r)
                    sO1[mi * 16 + fq * 4 + r][col] = fmaxf(acc[mi][ni][r] + bb, 0.0f);
            }
    }
    __syncthreads();

    // ---- stage 2: O2 = relu(O1 @ c2^T + b2)   M=32 N=64 K=128
    {
        f32x4 acc[2] = {};
#pragma unroll
        for (int kt = 0; kt < 4; ++kt) {
            f16x8 ah[2];
#pragma unroll
            for (int mi = 0; mi < 2; ++mi) {
                const float* p = &sO1[mi * 16 + fr][kt * 32 + fq * 8];
                f32x4 v0 = *(const f32x4*)p;
                f32x4 v1 = *(const f32x4*)(p + 4);
#pragma unroll
                for (int j = 0; j < 4; ++j) {
                    ah[mi][j]     = (_Float16)v0[j];
                    ah[mi][j + 4] = (_Float16)v1[j];
                }
            }
            size_t rb = (size_t)(wid * 16 + fr) * 128 + kt * 32 + fq * 8;
            f16x8 bw = *(const f16x8*)(c2w + rb);
#pragma unroll
            for (int mi = 0; mi < 2; ++mi)
                acc[mi] = __builtin_amdgcn_mfma_f32_16x16x32_f16(ah[mi], bw, acc[mi], 0, 0, 0);
        }
        int col = wid * 16 + fr;
        float bb = b2[col];
#pragma unroll
        for (int mi = 0; mi < 2; ++mi)
#pragma unroll
            for (int r = 0; r < 4; ++r)
                sO2[mi * 16 + fq * 4 + r][col] = fmaxf(acc[mi][r] + bb, 0.0f);
    }
    __syncthreads();

    // ---- stage 3: logits = O2 @ c3^T + b3
    if (wid < 2) {
        f32x4 acc = {};
#pragma unroll
        for (int kt = 0; kt < 2; ++kt) {
            const float* p = &sO2[wid * 16 + fr][kt * 32 + fq * 8];
            f32x4 v0 = *(const f32x4*)p;
            f32x4 v1 = *(const f32x4*)(p + 4);
            f16x8 ah;
#pragma unroll
            for (int j = 0; j < 4; ++j) {
                ah[j]     = (_Float16)v0[j];
                ah[j + 4] = (_Float16)v1[j];
            }
            size_t rb = (size_t)fr * 64 + kt * 32 + fq * 8;
            f16x8 bw = *(const f16x8*)(c3w + rb);
            acc = __builtin_amdgcn_mfma_f32_16x16x32_f16(ah, bw, acc, 0, 0, 0);
        }
        if (fr < 10) {
            float bb = b3[fr];
#pragma unroll
            for (int r = 0; r < 4; ++r) {
                int row = bm + wid * 16 + fq * 4 + r;
                if (row < NN) out[(size_t)row * 10 + fr] = acc[r] + bb;
            }
        }
    }
}

// ------------------------------------------------------------------
extern "C" void kernel_launch(void* const* d_in, const int* in_sizes, int n_in,
                              void* d_out, int out_size, void* d_ws, size_t ws_size,
                              hipStream_t stream)
{
    const float* x     = (const float*)d_in[0];
    const int*   eidx  = (const int*)d_in[1];
    const float* in_W  = (const float*)d_in[2];
    const float* in_b  = (const float*)d_in[3];
    const float* gcn_W = (const float*)d_in[4];
    const float* gcn_b = (const float*)d_in[5];
    const float* bn_g  = (const float*)d_in[6];
    const float* bn_be = (const float*)d_in[7];
    const float* bn_m  = (const float*)d_in[8];
    const float* bn_v  = (const float*)d_in[9];
    const float* c1_W  = (const float*)d_in[10];
    const float* c1_b  = (const float*)d_in[11];
    const float* c2_W  = (const float*)d_in[12];
    const float* c2_b  = (const float*)d_in[13];
    const float* c3_W  = (const float*)d_in[14];
    const float* c3_b  = (const float*)d_in[15];
    float* out = (float*)d_out;

    const int E = in_sizes[1] / 2;
    float* ws = (float*)d_ws;

    // ---- workspace layout ----
    _Float16* P   = (_Float16*)ws;              // 8 fp16 slices; dead after epi
    float*    h1  = ws;                         // residual 1 (aliases P)
    float*    h2  = ws + NPH;                   // residual 2 (aliases P)
    _Float16* hws = (_Float16*)(ws + 4 * NPH);  // NPH fp16 (gather table)
    _Float16* hh  = hws + NPH;
    _Float16* wi  = hh + NPH;         // 256x2048
    _Float16* gw  = wi + 524288;      // 768x256
    _Float16* c1w = gw + 196608;      // 128x256
    _Float16* c2w = c1w + 32768;      // 64x128
    _Float16* c3w = c2w + 8192;       // 16x64 (10 real rows)
    float*    bnA  = (float*)(c3w + 1024);      // 768
    float*    bnP2 = bnA + 768;                 // 768
    float*    dinv = bnP2 + 768;
    unsigned* cnt  = (unsigned*)(dinv + NN);
    unsigned* off  = cnt + NN;
    unsigned* cur  = off + NN + 1;
    unsigned* flag = cur + NN;
    int*      csr  = (int*)(flag + 4);

    // ---- graph prep + weight fp16 conversion + BN fold ----
    prep_split<<<3021, 256, 0, stream>>>(eidx, cnt, flag, in_W, gcn_W, c1_W, c2_W, c3_W,
                                         gcn_b, bn_g, bn_be, bn_m, bn_v,
                                         wi, gw, c1w, c2w, c3w, bnA, bnP2);
    count_edges<<<(E + 255) / 256, 256, 0, stream>>>(eidx, flag, cnt, E);
    scan_dinv<<<1, 1024, 0, stream>>>(cnt, off, cur, dinv, NN);
    fill_csr<<<(E + 255) / 256, 256, 0, stream>>>(eidx, flag, cur, csr, E);

    // ---- input projection ----
    inproj_gemm<<<dim3(NP / 64, 1, IPZ), 256, 0, stream>>>(x, wi, P);
    inproj_epi<<<(int)(NPH / 1024), 256, 0, stream>>>(P, in_b, hh);

    // ---- 3 GCN layers ----
    for (int i = 0; i < 3; ++i) {
        gemm_layer<<<dim3(NP / 64, 4), 256, 0, stream>>>(
            hh, gw + (size_t)i * 65536, dinv, hws);
        const float* res = (i == 0) ? nullptr : (i == 1 ? h1 : h2);
        float* hf = (i == 0) ? h1 : (i == 1 ? h2 : nullptr);
        gcn_aggregate<<<NN / 4, 256, 0, stream>>>(
            hws, res, dinv, off, csr,
            bnA + i * HID, bnP2 + i * HID, hf, hh);
    }

    // ---- fused classifier ----
    classifier<<<NP / 32, 256, 0, stream>>>(hh, c1w, c1_b,
                                            c2w, c2_b, c3w, c3_b, out);
}

// Round 20
// 218.311 us; speedup vs baseline: 1.1381x; 1.1381x over previous
//
#include <hip/hip_runtime.h>
#include <hip/hip_bf16.h>

#define NN   10000
#define NP   10048          // 157*64 padded rows
#define HID  256
#define BN_EPS 1e-5f
#define NPH  ((size_t)NP * 256)

typedef _Float16 f16x4 __attribute__((ext_vector_type(4)));
typedef _Float16 f16x8 __attribute__((ext_vector_type(8)));
typedef float    f32x4 __attribute__((ext_vector_type(4)));

__device__ __forceinline__ void gl_lds16(const void* gptr, void* lptr) {
    __builtin_amdgcn_global_load_lds(
        (const __attribute__((address_space(1))) void*)gptr,
        (__attribute__((address_space(3))) void*)lptr,
        16, 0, 0);
}

__device__ __forceinline__ f32x4 cvt4(const _Float16* p) {
    f16x4 t = *(const f16x4*)p;
    f32x4 r; r[0] = t[0]; r[1] = t[1]; r[2] = t[2]; r[3] = t[3];
    return r;
}

// 8-wide fp16 load -> two f32x4
__device__ __forceinline__ void cvt8(const _Float16* p, f32x4& lo, f32x4& hi) {
    f16x8 t = *(const f16x8*)p;
    lo[0] = t[0]; lo[1] = t[1]; lo[2] = t[2]; lo[3] = t[3];
    hi[0] = t[4]; hi[1] = t[5]; hi[2] = t[6]; hi[3] = t[7];
}

// ------------------------------------------------------------------
// Merged: cnt-zero + i64-layout detect (blocks 0..39), weight fp16
// conversion (blocks 40..3019), BN-fold precompute (block 3020).
__global__ void prep_split(const int* __restrict__ e, unsigned* __restrict__ cnt,
                           unsigned* __restrict__ flag,
                           const float* __restrict__ in_W, const float* __restrict__ gcn_W,
                           const float* __restrict__ c1_W, const float* __restrict__ c2_W,
                           const float* __restrict__ c3_W,
                           const float* __restrict__ gcn_b, const float* __restrict__ bn_g,
                           const float* __restrict__ bn_be, const float* __restrict__ bn_m,
                           const float* __restrict__ bn_v,
                           _Float16* __restrict__ wi, _Float16* __restrict__ gw,
                           _Float16* __restrict__ c1, _Float16* __restrict__ c2,
                           _Float16* __restrict__ c3,
                           float* __restrict__ bnA, float* __restrict__ bnP2) {
    if (blockIdx.x < 40) {
        int i = blockIdx.x * 256 + threadIdx.x;
        if (i < NN) cnt[i] = 0u;
        if (blockIdx.x == 0) {
            __shared__ int nz;
            if (threadIdx.x == 0) nz = 0;
            __syncthreads();
            if (e[2 * threadIdx.x + 1] != 0) nz = 1;
            __syncthreads();
            if (threadIdx.x == 0) *flag = (nz == 0) ? 1u : 0u;  // 1 => int64 layout
        }
        return;
    }
    if (blockIdx.x == 3020) {
#pragma unroll
        for (int it = 0; it < 3; ++it) {
            int idx = it * 256 + threadIdx.x;
            if (idx < 768) {
                float a = bn_g[idx] * rsqrtf(bn_v[idx] + BN_EPS);
                bnA[idx]  = a;
                bnP2[idx] = a * (gcn_b[idx] - bn_m[idx]) + bn_be[idx];
            }
        }
        return;
    }
    int idx = (blockIdx.x - 40) * 256 + threadIdx.x;
    float v; _Float16* d; int o;
    if (idx < 524288)      { v = in_W[idx];          d = wi; o = idx; }
    else if (idx < 720896) { o = idx - 524288; v = gcn_W[o]; d = gw; }
    else if (idx < 753664) { o = idx - 720896; v = c1_W[o];  d = c1; }
    else if (idx < 761856) { o = idx - 753664; v = c2_W[o];  d = c2; }
    else                   { o = idx - 761856; int r = o >> 6, c = o & 63;
                             v = (r < 10) ? c3_W[r * 64 + c] : 0.0f; d = c3; }
    d[o] = (_Float16)v;
}

__device__ __forceinline__ int edge_val(const int* e, unsigned f, long idx) {
    return f ? e[2 * idx] : e[idx];
}

__global__ void count_edges(const int* __restrict__ e, const unsigned* __restrict__ flag,
                            unsigned* __restrict__ cnt, int E) {
    int i = blockIdx.x * blockDim.x + threadIdx.x;
    if (i >= E) return;
    unsigned f = *flag;
    atomicAdd(&cnt[edge_val(e, f, (long)E + i)], 1u);
}

// single block, 1024 threads
__global__ void scan_dinv(const unsigned* __restrict__ cnt, unsigned* __restrict__ off,
                          unsigned* __restrict__ cur, float* __restrict__ dinv, int n) {
    __shared__ unsigned partial[1024];
    int t = threadIdx.x;
    int chunk = (n + 1023) / 1024;
    int lo = t * chunk;
    int hi = lo + chunk; if (hi > n) hi = n; if (lo > n) lo = n;
    unsigned s = 0;
    for (int i = lo; i < hi; ++i) s += cnt[i];
    partial[t] = s;
    __syncthreads();
    for (int d = 1; d < 1024; d <<= 1) {
        unsigned v = (t >= d) ? partial[t - d] : 0u;
        __syncthreads();
        partial[t] += v;
        __syncthreads();
    }
    unsigned base = (t == 0) ? 0u : partial[t - 1];
    for (int i = lo; i < hi; ++i) {
        off[i] = base; cur[i] = base;
        dinv[i] = rsqrtf((float)cnt[i] + 1.0f);
        base += cnt[i];
    }
    if (t == 1023) off[n] = base;
}

__global__ void fill_csr(const int* __restrict__ e, const unsigned* __restrict__ flag,
                         unsigned* __restrict__ cur, int* __restrict__ csr_src, int E) {
    int i = blockIdx.x * blockDim.x + threadIdx.x;
    if (i >= E) return;
    unsigned f = *flag;
    int src = edge_val(e, f, (long)i);
    int dst = edge_val(e, f, (long)E + i);
    unsigned pos = atomicAdd(&cur[dst], 1u);
    csr_src[pos] = src;
}

// ------------------------------------------------------------------
// Input projection (R17/R18 measured-best): BM=64 x BN=256, split-K=8,
// 2-phase pipelined, dbuf LDS. A(x) single fp16 staged via LDS; B single
// fp16 plane via global_load_lds. 1 MFMA pass/frag. LDS 40 KB. Partials FP16.
#define IPZ 8
#define IPKC 256
__global__ __launch_bounds__(256) void inproj_gemm(
    const float* __restrict__ A,
    const _Float16* __restrict__ B,
    _Float16* __restrict__ P)
{
    __shared__ __align__(16) _Float16 sA[2][2048];
    __shared__ __align__(16) _Float16 sB[2][8192];

    const int tid = threadIdx.x, wid = tid >> 6, lane = tid & 63;
    const int fr = lane & 15, fq = lane >> 4;
    const int bm = blockIdx.x * 64;
    const int kbase = blockIdx.z * IPKC;
    const int wn = wid * 64;

    f32x4 acc[4][4] = {};

    const int rs = tid >> 2, cq = tid & 3;
    const int gr = min(bm + rs, NN - 1);
    const float* aptr = A + (size_t)gr * 2048 + cq * 8;
    const int scA = rs * 32 + ((cq ^ ((rs >> 1) & 3)) << 3);
    const int brow_l = lane >> 2, bch = lane & 3;

    float av[8];
    int cur = 0;

    {   // prologue: stage tile 0
        float4 v0 = *(const float4*)(aptr + kbase);
        float4 v1 = *(const float4*)(aptr + kbase + 4);
        av[0]=v0.x; av[1]=v0.y; av[2]=v0.z; av[3]=v0.w;
        av[4]=v1.x; av[5]=v1.y; av[6]=v1.z; av[7]=v1.w;
#pragma unroll
        for (int j = 0; j < 4; ++j) {
            int slice = wid * 4 + j;
            int row = slice * 16 + brow_l;
            int lc = bch ^ ((row >> 1) & 3);
            gl_lds16(B + (size_t)row * 2048 + kbase + lc * 8, &sB[0][slice * 512]);
        }
        f16x8 hv;
#pragma unroll
        for (int j = 0; j < 8; ++j) hv[j] = (_Float16)av[j];
        *(f16x8*)&sA[0][scA] = hv;
    }
    __syncthreads();

    for (int kt = 0; kt < IPKC / 32; ++kt) {
        const bool more = (kt + 1) < IPKC / 32;
        const int nk = kbase + (kt + 1) * 32;
        if (more) {
            float4 v0 = *(const float4*)(aptr + nk);
            float4 v1 = *(const float4*)(aptr + nk + 4);
            av[0]=v0.x; av[1]=v0.y; av[2]=v0.z; av[3]=v0.w;
            av[4]=v1.x; av[5]=v1.y; av[6]=v1.z; av[7]=v1.w;
#pragma unroll
            for (int j = 0; j < 4; ++j) {
                int slice = wid * 4 + j;
                int row = slice * 16 + brow_l;
                int lc = bch ^ ((row >> 1) & 3);
                gl_lds16(B + (size_t)row * 2048 + nk + lc * 8, &sB[cur ^ 1][slice * 512]);
            }
        }
        f16x8 b[4];
#pragma unroll
        for (int ni = 0; ni < 4; ++ni) {
            int r = wn + ni * 16 + fr;
            b[ni] = *(const f16x8*)&sB[cur][r * 32 + ((fq ^ ((r >> 1) & 3)) << 3)];
        }
#pragma unroll
        for (int mi = 0; mi < 4; ++mi) {
            int r = mi * 16 + fr;
            f16x8 a = *(const f16x8*)&sA[cur][r * 32 + ((fq ^ ((r >> 1) & 3)) << 3)];
#pragma unroll
            for (int ni = 0; ni < 4; ++ni)
                acc[mi][ni] = __builtin_amdgcn_mfma_f32_16x16x32_f16(a, b[ni], acc[mi][ni], 0, 0, 0);
        }
        if (more) {
            f16x8 hv;
#pragma unroll
            for (int j = 0; j < 8; ++j) hv[j] = (_Float16)av[j];
            *(f16x8*)&sA[cur ^ 1][scA] = hv;
        }
        __syncthreads();
        cur ^= 1;
    }

    _Float16* Pz = P + (size_t)blockIdx.z * NPH;
#pragma unroll
    for (int mi = 0; mi < 4; ++mi) {
        int row0 = bm + mi * 16 + fq * 4;
#pragma unroll
        for (int ni = 0; ni < 4; ++ni) {
            int col = wn + ni * 16 + fr;
#pragma unroll
            for (int r = 0; r < 4; ++r)
                Pz[(size_t)(row0 + r) * 256 + col] = (_Float16)acc[mi][ni][r];
        }
    }
}

// reduce 8 fp16 partials + bias + relu -> single fp16 plane (zero pad rows)
__global__ void inproj_epi(const _Float16* __restrict__ P, const float* __restrict__ b,
                           _Float16* __restrict__ hh) {
    int t = blockIdx.x * 256 + threadIdx.x;
    size_t idx = (size_t)t * 4;
    int row = (int)(idx >> 8), col = (int)(idx & 255);
    float v[4] = {0, 0, 0, 0};
    if (row < NN) {
        f32x4 a0 = cvt4(P + idx)           + cvt4(P + idx + NPH);
        f32x4 a1 = cvt4(P + idx + 2 * NPH) + cvt4(P + idx + 3 * NPH);
        f32x4 a2 = cvt4(P + idx + 4 * NPH) + cvt4(P + idx + 5 * NPH);
        f32x4 a3 = cvt4(P + idx + 6 * NPH) + cvt4(P + idx + 7 * NPH);
        f32x4 bb = *(const f32x4*)(b + col);
#pragma unroll
        for (int j = 0; j < 4; ++j)
            v[j] = fmaxf((a0[j] + a1[j]) + (a2[j] + a3[j]) + bb[j], 0.0f);
    }
    f16x4 hv;
#pragma unroll
    for (int j = 0; j < 4; ++j) hv[j] = (_Float16)v[j];
    *(f16x4*)&hh[idx] = hv;
}

// ------------------------------------------------------------------
// Layer GEMM (K=256): no LDS, per-lane direct fragment loads.
// A = h single fp16, B = single fp16 weight plane; 1 pass.
// Epilogue pre-scales by dinv[row] and emits hws as FP16.
__global__ __launch_bounds__(256) void gemm_layer(
    const _Float16* __restrict__ Ah,
    const _Float16* __restrict__ Bw,
    const float* __restrict__ dinv, _Float16* __restrict__ Cw)
{
    const int tid = threadIdx.x, wid = tid >> 6, lane = tid & 63;
    const int fr = lane & 15, fq = lane >> 4;
    const int wr = wid >> 1, wc = wid & 1;
    const int bm = blockIdx.x * 64, bn = blockIdx.y * 64;

    f32x4 acc[2][2] = {};
    size_t ra[2], rb[2];
#pragma unroll
    for (int mi = 0; mi < 2; ++mi) ra[mi] = (size_t)(bm + wr * 32 + mi * 16 + fr) * 256 + fq * 8;
#pragma unroll
    for (int ni = 0; ni < 2; ++ni) rb[ni] = (size_t)(bn + wc * 32 + ni * 16 + fr) * 256 + fq * 8;

#pragma unroll
    for (int kt = 0; kt < 8; ++kt) {
        f16x8 ah[2], bw[2];
#pragma unroll
        for (int mi = 0; mi < 2; ++mi)
            ah[mi] = *(const f16x8*)(Ah + ra[mi] + kt * 32);
#pragma unroll
        for (int ni = 0; ni < 2; ++ni)
            bw[ni] = *(const f16x8*)(Bw + rb[ni] + kt * 32);
#pragma unroll
        for (int mi = 0; mi < 2; ++mi)
#pragma unroll
            for (int ni = 0; ni < 2; ++ni)
                acc[mi][ni] = __builtin_amdgcn_mfma_f32_16x16x32_f16(ah[mi], bw[ni], acc[mi][ni], 0, 0, 0);
    }

    float dv[2][4];
#pragma unroll
    for (int mi = 0; mi < 2; ++mi)
#pragma unroll
        for (int r = 0; r < 4; ++r) {
            int row = bm + wr * 32 + mi * 16 + fq * 4 + r;
            dv[mi][r] = (row < NN) ? dinv[row] : 0.0f;
        }

#pragma unroll
    for (int mi = 0; mi < 2; ++mi)
#pragma unroll
        for (int ni = 0; ni < 2; ++ni) {
            int col = bn + wc * 32 + ni * 16 + fr;
#pragma unroll
            for (int r = 0; r < 4; ++r) {
                int row = bm + wr * 32 + mi * 16 + fq * 4 + r;
                if (row < NN)
                    Cw[(size_t)row * 256 + col] = (_Float16)(acc[mi][ni][r] * dv[mi][r]);
            }
        }
}

// ------------------------------------------------------------------
// GCN aggregate v7: wave-per-node, TWO edges in flight per iteration.
//   out = relu(bnA*(dn*acc) + bnP2) (+ res); emits single fp16 plane.
__global__ __launch_bounds__(256) void gcn_aggregate(
    const _Float16* __restrict__ hws, const float* __restrict__ res,
    const float* __restrict__ dinv, const unsigned* __restrict__ off,
    const int* __restrict__ csr,
    const float* __restrict__ bnA, const float* __restrict__ bnP2,
    float* __restrict__ hf, _Float16* __restrict__ hh)
{
    const int wid = threadIdx.x >> 6, l = threadIdx.x & 63;
    const int node = blockIdx.x * 4 + wid;            // grid = 2500 blocks
    const int half = l >> 5;                          // 0 or 1
    const int q = l & 31;                             // lane-in-half
    const int f = q << 3;                             // feature base 0..248 (8 feats)
    const size_t rowf = (size_t)node * HID + f;

    const float dn = dinv[node];
    const unsigned j0 = off[node], j1 = off[node + 1];
    const unsigned deg = j1 - j0;

    f32x4 a0l = {0,0,0,0}, a0h = {0,0,0,0}, a1l = {0,0,0,0}, a1h = {0,0,0,0};
    f32x4 a2l = {0,0,0,0}, a2h = {0,0,0,0}, a3l = {0,0,0,0}, a3h = {0,0,0,0};

    if (half == 0) {   // self term in half 0
        f32x4 lo, hi; cvt8(hws + rowf, lo, hi);
        a0l += lo; a0h += hi;
    }

    unsigned i = (unsigned)half;
    for (; i + 8 <= deg; i += 8) {     // 4 edges per half per iter (stride 2)
        int s0 = csr[j0 + i];
        int s1 = csr[j0 + i + 2];
        int s2 = csr[j0 + i + 4];
        int s3 = csr[j0 + i + 6];
        f32x4 lo, hi;
        cvt8(hws + (size_t)s0 * HID + f, lo, hi); a0l += lo; a0h += hi;
        cvt8(hws + (size_t)s1 * HID + f, lo, hi); a1l += lo; a1h += hi;
        cvt8(hws + (size_t)s2 * HID + f, lo, hi); a2l += lo; a2h += hi;
        cvt8(hws + (size_t)s3 * HID + f, lo, hi); a3l += lo; a3h += hi;
    }
    for (; i < deg; i += 2) {
        int s = csr[j0 + i];
        f32x4 lo, hi;
        cvt8(hws + (size_t)s * HID + f, lo, hi); a1l += lo; a1h += hi;
    }

    f32x4 accl = (a0l + a1l) + (a2l + a3l);
    f32x4 acch = (a0h + a1h) + (a2h + a3h);

#pragma unroll
    for (int j = 0; j < 4; ++j) {
        accl[j] += __shfl_xor((float)accl[j], 32);
        acch[j] += __shfl_xor((float)acch[j], 32);
    }
    if (half) return;

    f32x4 alL = *(const f32x4*)(bnA + f);
    f32x4 alH = *(const f32x4*)(bnA + f + 4);
    f32x4 p4L = *(const f32x4*)(bnP2 + f);
    f32x4 p4H = *(const f32x4*)(bnP2 + f + 4);
    f32x4 rL = {0,0,0,0}, rH = {0,0,0,0};
    if (res) {
        rL = *(const f32x4*)(res + rowf);
        rH = *(const f32x4*)(res + rowf + 4);
    }

    f32x4 oL, oH;
    f16x8 hv;
#pragma unroll
    for (int j = 0; j < 4; ++j) {
        float t = alL[j] * (dn * accl[j]) + p4L[j];
        t = fmaxf(t, 0.0f) + rL[j];
        oL[j] = t; hv[j] = (_Float16)t;
        float u = alH[j] * (dn * acch[j]) + p4H[j];
        u = fmaxf(u, 0.0f) + rH[j];
        oH[j] = u; hv[j + 4] = (_Float16)u;
    }
    if (hf) {
        *(f32x4*)(hf + rowf)     = oL;
        *(f32x4*)(hf + rowf + 4) = oH;
    }
    *(f16x8*)&hh[rowf] = hv;
}

// ------------------------------------------------------------------
// Fused classifier: 32-row tile, h -> O1(LDS) -> O2(LDS) -> logits.
__global__ __launch_bounds__(256) void classifier(
    const _Float16* __restrict__ Ah,
    const _Float16* __restrict__ c1w, const float* __restrict__ b1,
    const _Float16* __restrict__ c2w, const float* __restrict__ b2,
    const _Float16* __restrict__ c3w, const float* __restrict__ b3,
    float* __restrict__ out)
{
    __shared__ __align__(16) float sO1[32][132];
    __shared__ __align__(16) float sO2[32][68];

    const int tid = threadIdx.x, wid = tid >> 6, lane = tid & 63;
    const int fr = lane & 15, fq = lane >> 4;
    const int bm = blockIdx.x * 32;

    // ---- stage 1: O1 = relu(h @ c1^T + b1)   M=32 N=128 K=256
    {
        f32x4 acc[2][2] = {};
        size_t ra[2], rb[2];
#pragma unroll
        for (int mi = 0; mi < 2; ++mi) ra[mi] = (size_t)(bm + mi * 16 + fr) * 256 + fq * 8;
#pragma unroll
        for (int ni = 0; ni < 2; ++ni) rb[ni] = (size_t)(wid * 32 + ni * 16 + fr) * 256 + fq * 8;
#pragma unroll
        for (int kt = 0; kt < 8; ++kt) {
            f16x8 ah[2], bw[2];
#pragma unroll
            for (int mi = 0; mi < 2; ++mi)
                ah[mi] = *(const f16x8*)(Ah + ra[mi] + kt * 32);
#pragma unroll
            for (int ni = 0; ni < 2; ++ni)
                bw[ni] = *(const f16x8*)(c1w + rb[ni] + kt * 32);
#pragma unroll
            for (int mi = 0; mi < 2; ++mi)
#pragma unroll
                for (int ni = 0; ni < 2; ++ni)
                    acc[mi][ni] = __builtin_amdgcn_mfma_f32_16x16x32_f16(ah[mi], bw[ni], acc[mi][ni], 0, 0, 0);
        }
#pragma unroll
        for (int mi = 0; mi < 2; ++mi)
#pragma unroll
            for (int ni = 0; ni < 2; ++ni) {
                int col = wid * 32 + ni * 16 + fr;
                float bb = b1[col];
#pragma unroll
                for (int r = 0; r < 4; ++r)
                    sO1[mi * 16 + fq * 4 + r][col] = fmaxf(acc[mi][ni][r] + bb, 0.0f);
            }
    }
    __syncthreads();

    // ---- stage 2: O2 = relu(O1 @ c2^T + b2)   M=32 N=64 K=128
    {
        f32x4 acc[2] = {};
#pragma unroll
        for (int kt = 0; kt < 4; ++kt) {
            f16x8 ah[2];
#pragma unroll
            for (int mi = 0; mi < 2; ++mi) {
                const float* p = &sO1[mi * 16 + fr][kt * 32 + fq * 8];
                f32x4 v0 = *(const f32x4*)p;
                f32x4 v1 = *(const f32x4*)(p + 4);
#pragma unroll
                for (int j = 0; j < 4; ++j) {
                    ah[mi][j]     = (_Float16)v0[j];
                    ah[mi][j + 4] = (_Float16)v1[j];
                }
            }
            size_t rb = (size_t)(wid * 16 + fr) * 128 + kt * 32 + fq * 8;
            f16x8 bw = *(const f16x8*)(c2w + rb);
#pragma unroll
            for (int mi = 0; mi < 2; ++mi)
                acc[mi] = __builtin_amdgcn_mfma_f32_16x16x32_f16(ah[mi], bw, acc[mi], 0, 0, 0);
        }
        int col = wid * 16 + fr;
        float bb = b2[col];
#pragma unroll
        for (int mi = 0; mi < 2; ++mi)
#pragma unroll
            for (int r = 0; r < 4; ++r)
                sO2[mi * 16 + fq * 4 + r][col] = fmaxf(acc[mi][r] + bb, 0.0f);
    }
    __syncthreads();

    // ---- stage 3: logits = O2 @ c3^T + b3
    if (wid < 2) {
        f32x4 acc = {};
#pragma unroll
        for (int kt = 0; kt < 2; ++kt) {
            const float* p = &sO2[wid * 16 + fr][kt * 32 + fq * 8];
            f32x4 v0 = *(const f32x4*)p;
            f32x4 v1 = *(const f32x4*)(p + 4);
            f16x8 ah;
#pragma unroll
            for (int j = 0; j < 4; ++j) {
                ah[j]     = (_Float16)v0[j];
                ah[j + 4] = (_Float16)v1[j];
            }
            size_t rb = (size_t)fr * 64 + kt * 32 + fq * 8;
            f16x8 bw = *(const f16x8*)(c3w + rb);
            acc = __builtin_amdgcn_mfma_f32_16x16x32_f16(ah, bw, acc, 0, 0, 0);
        }
        if (fr < 10) {
            float bb = b3[fr];
#pragma unroll
            for (int r = 0; r < 4; ++r) {
                int row = bm + wid * 16 + fq * 4 + r;
                if (row < NN) out[(size_t)row * 10 + fr] = acc[r] + bb;
            }
        }
    }
}

// ------------------------------------------------------------------
extern "C" void kernel_launch(void* const* d_in, const int* in_sizes, int n_in,
                              void* d_out, int out_size, void* d_ws, size_t ws_size,
                              hipStream_t stream)
{
    const float* x     = (const float*)d_in[0];
    const int*   eidx  = (const int*)d_in[1];
    const float* in_W  = (const float*)d_in[2];
    const float* in_b  = (const float*)d_in[3];
    const float* gcn_W = (const float*)d_in[4];
    const float* gcn_b = (const float*)d_in[5];
    const float* bn_g  = (const float*)d_in[6];
    const float* bn_be = (const float*)d_in[7];
    const float* bn_m  = (const float*)d_in[8];
    const float* bn_v  = (const float*)d_in[9];
    const float* c1_W  = (const float*)d_in[10];
    const float* c1_b  = (const float*)d_in[11];
    const float* c2_W  = (const float*)d_in[12];
    const float* c2_b  = (const float*)d_in[13];
    const float* c3_W  = (const float*)d_in[14];
    const float* c3_b  = (const float*)d_in[15];
    float* out = (float*)d_out;

    const int E = in_sizes[1] / 2;
    float* ws = (float*)d_ws;

    // ---- workspace layout ----
    _Float16* P   = (_Float16*)ws;              // 8 fp16 slices; dead after epi
    float*    h1  = ws;                         // residual 1 (aliases P)
    float*    h2  = ws + NPH;                   // residual 2 (aliases P)
    _Float16* hws = (_Float16*)(ws + 4 * NPH);  // NPH fp16 (gather table)
    _Float16* hh  = hws + NPH;
    _Float16* wi  = hh + NPH;         // 256x2048
    _Float16* gw  = wi + 524288;      // 768x256
    _Float16* c1w = gw + 196608;      // 128x256
    _Float16* c2w = c1w + 32768;      // 64x128
    _Float16* c3w = c2w + 8192;       // 16x64 (10 real rows)
    float*    bnA  = (float*)(c3w + 1024);      // 768
    float*    bnP2 = bnA + 768;                 // 768
    float*    dinv = bnP2 + 768;
    unsigned* cnt  = (unsigned*)(dinv + NN);
    unsigned* off  = cnt + NN;
    unsigned* cur  = off + NN + 1;
    unsigned* flag = cur + NN;
    int*      csr  = (int*)(flag + 4);

    // ---- graph prep + weight fp16 conversion + BN fold ----
    prep_split<<<3021, 256, 0, stream>>>(eidx, cnt, flag, in_W, gcn_W, c1_W, c2_W, c3_W,
                                         gcn_b, bn_g, bn_be, bn_m, bn_v,
                                         wi, gw, c1w, c2w, c3w, bnA, bnP2);
    count_edges<<<(E + 255) / 256, 256, 0, stream>>>(eidx, flag, cnt, E);
    scan_dinv<<<1, 1024, 0, stream>>>(cnt, off, cur, dinv, NN);
    fill_csr<<<(E + 255) / 256, 256, 0, stream>>>(eidx, flag, cur, csr, E);

    // ---- input projection ----
    inproj_gemm<<<dim3(NP / 64, 1, IPZ), 256, 0, stream>>>(x, wi, P);
    inproj_epi<<<(int)(NPH / 1024), 256, 0, stream>>>(P, in_b, hh);

    // ---- 3 GCN layers ----
    for (int i = 0; i < 3; ++i) {
        gemm_layer<<<dim3(NP / 64, 4), 256, 0, stream>>>(
            hh, gw + (size_t)i * 65536, dinv, hws);
        const float* res = (i == 0) ? nullptr : (i == 1 ? h1 : h2);
        float* hf = (i == 0) ? h1 : (i == 1 ? h2 : nullptr);
        gcn_aggregate<<<NN / 4, 256, 0, stream>>>(
            hws, res, dinv, off, csr,
            bnA + i * HID, bnP2 + i * HID, hf, hh);
    }

    // ---- fused classifier ----
    classifier<<<NP / 32, 256, 0, stream>>>(hh, c1w, c1_b,
                                            c2w, c2_b, c3w, c3_b, out);
}